// Round 13
// baseline (616.634 us; speedup 1.0000x reference)
//
#include <hip/hip_runtime.h>
#include <hip/hip_bf16.h>
#include <math.h>

// Problem constants (from reference setup_inputs)
#define B_TOTAL   131072
#define C_IN      64
#define H_DIM     256
#define K_KNOTS   32
#define DH        8
#define P_DIM     768      // 3*K*Dh per row
#define R_ROWS    64       // rows per block
#define NTHREADS  512

#define TWO_PI_F       6.2831853071795864769f
#define MIN_WF         1e-3f
#define MIN_HF         1e-3f
#define MIN_DF         1e-3f
#define DERIV_SHIFT_F  0.54132485461292f   // log(e - 1)

typedef __attribute__((ext_vector_type(8))) short bf16x8;
typedef __attribute__((ext_vector_type(4))) float f32x4;

// ---------------- LDS layout (bytes) ----------------
// Staging (phases 0-2):
//  sX_hi/lo : 64 rows x 64 bf16  (128B row, 16B slots XOR-swizzled)   [0,8192)+[8192,16384)
//  sH_hi/lo : 64 rows x 256 bf16 (512B row, 16B slots XOR-swizzled)   [16384,49152)+[49152,81920)
// Spline staging (after GEMM2 MFMA loop; sX/sH dead -> alias at 0):
//  sP : 16 rows x 780 f32 (dh stride 97), four passes of 16 rows      [0, 49920)
// LDS_BYTES = 81920 exactly -> 2 blocks/CU in the 160 KiB pool.
#define SXH_BYTE  0
#define SXL_BYTE  8192
#define SHH_BYTE  16384
#define SHL_BYTE  49152
#define LDS_BYTES 81920

// ws layout: hi/lo packed fragments (bf16 as short)
// W2p[((nt*8 + kc)*64 + lane)*8 + j] = bf16(W2[(kc*32 + (lane>>4)*8 + j) * 768 + nt*16 + (lane&15)])
// W1p[((nt*2 + kc)*64 + lane)*8 + j] = bf16(W1[(kc*32 + (lane>>4)*8 + j) * 256 + nt*16 + (lane&15)])
#define W2P_ELEMS 196608   // 48*8*64*8
#define W1P_ELEMS 16384    // 16*2*64*8

__device__ __forceinline__ short f2bf(float x) {
    __hip_bfloat16 h = __float2bfloat16(x);
    return *reinterpret_cast<short*>(&h);
}
__device__ __forceinline__ float bf2f(short s) {
    unsigned u = ((unsigned)(unsigned short)s) << 16;
    return __uint_as_float(u);
}

__device__ __forceinline__ float softplus_f(float x) {
    return (x > 15.f) ? x : log1pf(__expf(x));
}

// ---------------- weight pack kernel (hi/lo split) ----------------
__global__ __launch_bounds__(256)
void pack_weights(const float* __restrict__ W1, const float* __restrict__ W2,
                  short* __restrict__ W1p_hi, short* __restrict__ W1p_lo,
                  short* __restrict__ W2p_hi, short* __restrict__ W2p_lo)
{
    const int idx = blockIdx.x * 256 + threadIdx.x;
    if (idx < W2P_ELEMS) {
        const int j  = idx & 7;
        const int l  = (idx >> 3) & 63;
        const int c  = idx >> 9;          // nt*8 + kc
        const int kc = c & 7;
        const int nt = c >> 3;
        const int k  = kc * 32 + (l >> 4) * 8 + j;
        const int n  = nt * 16 + (l & 15);
        const float wv = W2[k * P_DIM + n];
        const short hi = f2bf(wv);
        W2p_hi[idx] = hi;
        W2p_lo[idx] = f2bf(wv - bf2f(hi));
    } else {
        const int i2 = idx - W2P_ELEMS;
        if (i2 < W1P_ELEMS) {
            const int j  = i2 & 7;
            const int l  = (i2 >> 3) & 63;
            const int c  = i2 >> 9;       // nt*2 + kc
            const int kc = c & 1;
            const int nt = c >> 1;
            const int k  = kc * 32 + (l >> 4) * 8 + j;
            const int n  = nt * 16 + (l & 15);
            const float wv = W1[k * H_DIM + n];
            const short hi = f2bf(wv);
            W1p_hi[i2] = hi;
            W1p_lo[i2] = f2bf(wv - bf2f(hi));
        }
    }
}

// ---------------- fused main kernel ----------------
__global__ __launch_bounds__(NTHREADS, 4)   // 4 waves/SIMD -> 2 blocks/CU (VGPR<=128)
void spline_mfma(const float* __restrict__ theta,
                 const float* __restrict__ X,
                 const short* __restrict__ W1p_hi,
                 const short* __restrict__ W1p_lo,
                 const float* __restrict__ b1,
                 const short* __restrict__ W2p_hi,
                 const short* __restrict__ W2p_lo,
                 const float* __restrict__ b2,
                 const float* __restrict__ eta,
                 float* __restrict__ out)
{
    extern __shared__ float smem[];
    char*  sXh = reinterpret_cast<char*>(smem) + SXH_BYTE;
    char*  sXl = reinterpret_cast<char*>(smem) + SXL_BYTE;
    char*  sHh = reinterpret_cast<char*>(smem) + SHH_BYTE;
    char*  sHl = reinterpret_cast<char*>(smem) + SHL_BYTE;
    float* sP  = smem;   // aliases sX/sH after GEMM2 MFMA loop

    const int t    = threadIdx.x;
    const int r0   = blockIdx.x * R_ROWS;
    const int lane = t & 63;
    const int w    = t >> 6;    // wave 0..7

    // ---- Phase 0: stage X tile (64x64 f32) -> sX hi/lo bf16, XOR-swizzled ----
    #pragma unroll
    for (int i = 0; i < 2; ++i) {
        const int idx = t + i * NTHREADS;            // 0..1023
        const float4 v = reinterpret_cast<const float4*>(X + (size_t)r0 * C_IN)[idx];
        const int row = idx >> 4;
        const int c0  = (idx & 15) * 4;              // starting col (multiple of 4)
        const int slot = c0 >> 3;                    // 16B slot within 128B row
        const int byte = row * 128 + ((slot ^ (row & 7)) << 4) + ((c0 & 4) << 1);
        short4 hv, lv;
        hv.x = f2bf(v.x); lv.x = f2bf(v.x - bf2f(hv.x));
        hv.y = f2bf(v.y); lv.y = f2bf(v.y - bf2f(hv.y));
        hv.z = f2bf(v.z); lv.z = f2bf(v.z - bf2f(hv.z));
        hv.w = f2bf(v.w); lv.w = f2bf(v.w - bf2f(hv.w));
        *reinterpret_cast<short4*>(sXh + byte) = hv;
        *reinterpret_cast<short4*>(sXl + byte) = lv;
    }
    __syncthreads();

    // ---- Phase 1: GEMM1  H = relu(X @ W1 + b1) -> sH hi/lo bf16 swizzled ----
    // wave w: n-tiles {2w, 2w+1}, m-tiles 0..3. K=64 -> kc in {0,1}.
    {
        f32x4 acc[4][2] = {};   // [mt][ntl]
        #pragma unroll
        for (int kc = 0; kc < 2; ++kc) {
            bf16x8 ah[4], al[4];
            #pragma unroll
            for (int mt = 0; mt < 4; ++mt) {
                const int arow = mt * 16 + (lane & 15);
                const int aslot = kc * 4 + (lane >> 4);
                const int off = arow * 128 + ((aslot ^ (arow & 7)) << 4);
                ah[mt] = *reinterpret_cast<const bf16x8*>(sXh + off);
                al[mt] = *reinterpret_cast<const bf16x8*>(sXl + off);
            }
            #pragma unroll
            for (int ntl = 0; ntl < 2; ++ntl) {
                const int nt = 2 * w + ntl;
                const int boff = ((nt * 2 + kc) * 64 + lane) << 3;
                const bf16x8 bh = *reinterpret_cast<const bf16x8*>(W1p_hi + boff);
                const bf16x8 bl = *reinterpret_cast<const bf16x8*>(W1p_lo + boff);
                #pragma unroll
                for (int mt = 0; mt < 4; ++mt) {
                    acc[mt][ntl] = __builtin_amdgcn_mfma_f32_16x16x32_bf16(ah[mt], bh, acc[mt][ntl], 0, 0, 0);
                    acc[mt][ntl] = __builtin_amdgcn_mfma_f32_16x16x32_bf16(ah[mt], bl, acc[mt][ntl], 0, 0, 0);
                    acc[mt][ntl] = __builtin_amdgcn_mfma_f32_16x16x32_bf16(al[mt], bh, acc[mt][ntl], 0, 0, 0);
                }
            }
        }
        #pragma unroll
        for (int ntl = 0; ntl < 2; ++ntl) {
            const int col  = (2 * w + ntl) * 16 + (lane & 15);
            const float bias = b1[col];
            #pragma unroll
            for (int mt = 0; mt < 4; ++mt) {
                #pragma unroll
                for (int r = 0; r < 4; ++r) {
                    const int row = mt * 16 + (lane >> 4) * 4 + r;
                    float h = acc[mt][ntl][r] + bias;
                    h = h > 0.f ? h : 0.f;
                    const int byte = row * 512 + ((((col >> 3) ^ (row & 7)) << 4)) + ((col & 7) * 2);
                    const short hh = f2bf(h);
                    *reinterpret_cast<short*>(sHh + byte) = hh;
                    *reinterpret_cast<short*>(sHl + byte) = f2bf(h - bf2f(hh));
                }
            }
        }
    }
    __syncthreads();

    // ---- Phase 2: GEMM2  P = (H @ W2 + b2) * eta ----
    // wave w: n-tiles w*6 .. w*6+5 (cols 96w..96w+95 => dh == w), m-tiles 0..3. K=256 -> kc 0..7.
    f32x4 acc2[4][6] = {};
    {
        const int ntbase = w * 6;
        #pragma unroll
        for (int kc = 0; kc < 8; ++kc) {
            bf16x8 ah[4], al[4];
            #pragma unroll
            for (int mt = 0; mt < 4; ++mt) {
                const int arow = mt * 16 + (lane & 15);
                const int aslot = kc * 4 + (lane >> 4);       // 32 slots per 512B row
                const int off = arow * 512 + ((aslot ^ (arow & 7)) << 4);
                ah[mt] = *reinterpret_cast<const bf16x8*>(sHh + off);
                al[mt] = *reinterpret_cast<const bf16x8*>(sHl + off);
            }
            #pragma unroll
            for (int ntl = 0; ntl < 6; ++ntl) {
                const int nt = ntbase + ntl;
                const int boff = ((nt * 8 + kc) * 64 + lane) << 3;
                const bf16x8 bh = *reinterpret_cast<const bf16x8*>(W2p_hi + boff);
                const bf16x8 bl = *reinterpret_cast<const bf16x8*>(W2p_lo + boff);
                #pragma unroll
                for (int mt = 0; mt < 4; ++mt) {
                    acc2[mt][ntl] = __builtin_amdgcn_mfma_f32_16x16x32_bf16(ah[mt], bh, acc2[mt][ntl], 0, 0, 0);
                    acc2[mt][ntl] = __builtin_amdgcn_mfma_f32_16x16x32_bf16(ah[mt], bl, acc2[mt][ntl], 0, 0, 0);
                    acc2[mt][ntl] = __builtin_amdgcn_mfma_f32_16x16x32_bf16(al[mt], bh, acc2[mt][ntl], 0, 0, 0);
                }
            }
        }
    }
    // hoist epilogue constants (6 biases + eta) before the pass loop
    const float ev = eta[0];
    float bias2[6];
    #pragma unroll
    for (int ntl = 0; ntl < 6; ++ntl)
        bias2[ntl] = b2[(w * 6 + ntl) * 16 + (lane & 15)];
    __syncthreads();   // all sH reads done -> safe to overwrite with sP

    // ---- Phases 3+4: epilogue -> sP (f32) + spline, four 16-row passes ----
    #pragma unroll
    for (int hp = 0; hp < 4; ++hp) {
        // epilogue: rows hp*16 .. hp*16+15  (mt = hp)
        {
            #pragma unroll
            for (int ntl = 0; ntl < 6; ++ntl) {
                const int col = (w * 6 + ntl) * 16 + (lane & 15);
                const int dh  = w;               // cols 96w..96w+95 -> dh == w
                const int j   = col - dh * 96;
                #pragma unroll
                for (int r = 0; r < 4; ++r) {
                    const int rowl = (lane >> 4) * 4 + r;
                    sP[rowl * 780 + dh * 97 + j] = (acc2[hp][ntl][r] + bias2[ntl]) * ev;
                }
            }
        }
        __syncthreads();

        // spline: one thread per (row, dh); threads 0..127
        if (t < 128) {
            const int rowl = t >> 3;
            const int dh   = t & 7;
            const float* p = &sP[rowl * 780 + dh * 97];  // [0..31]=uw [32..63]=uh [64..95]=ud
            const int gi = (r0 + hp * 16 + rowl) * DH + dh;
            const float th = theta[gi];

            // pass 1: maxes
            float mw = -1e30f, mh = -1e30f;
            #pragma unroll 1
            for (int k = 0; k < K_KNOTS; ++k) {
                mw = fmaxf(mw, p[k]);
                mh = fmaxf(mh, p[32 + k]);
            }
            // pass 2: softmax denominators
            float sw = 0.f, sh = 0.f;
            #pragma unroll 1
            for (int k = 0; k < K_KNOTS; ++k) {
                sw += __expf(p[k] - mw);
                sh += __expf(p[32 + k] - mh);
            }
            const float scw = (1.f - MIN_WF * (float)K_KNOTS) / sw;
            const float sch = (1.f - MIN_HF * (float)K_KNOTS) / sh;

            // pass 3: bin walk (replicates reference cumsum->pad->*2pi->set-ends->diff)
            float pw = 0.f, ph = 0.f;
            float cumw = 0.f, cumh = 0.f;
            float in_cumw = 0.f, in_w = 1.f, in_cumh = 0.f, in_h = 1.f;
            int idx = 0;
            #pragma unroll 1
            for (int k = 0; k < K_KNOTS; ++k) {
                pw += MIN_WF + __expf(p[k] - mw) * scw;
                ph += MIN_HF + __expf(p[32 + k] - mh) * sch;
                const float cumw1 = (k == K_KNOTS - 1) ? TWO_PI_F : TWO_PI_F * pw;
                const float cumh1 = (k == K_KNOTS - 1) ? TWO_PI_F : TWO_PI_F * ph;
                if (th >= cumw) {
                    idx = k;
                    in_cumw = cumw; in_w = cumw1 - cumw;
                    in_cumh = cumh; in_h = cumh1 - cumh;
                }
                cumw = cumw1; cumh = cumh1;
            }

            const float ud0 = p[64 + idx] + DERIV_SHIFT_F;
            const int idx1 = (idx + 1) & (K_KNOTS - 1);
            const float ud1 = p[64 + idx1] + DERIV_SHIFT_F;
            const float in_d  = MIN_DF + softplus_f(ud0);
            const float in_d1 = MIN_DF + softplus_f(ud1);

            const float tt    = (th - in_cumw) / in_w;
            const float t1mt  = tt * (1.f - tt);
            const float delta = in_h / in_w;
            const float num   = in_h * (delta * tt * tt + in_d * t1mt);
            const float den   = delta + (in_d + in_d1 - 2.f * delta) * t1mt;
            const float outv  = in_cumh + num / den;
            const float omt   = 1.f - tt;
            const float dnum  = delta * delta * (in_d1 * tt * tt + 2.f * delta * t1mt + in_d * omt * omt);
            const float lad   = __logf(dnum) - 2.f * __logf(den);

            out[gi]                = outv;
            out[B_TOTAL * DH + gi] = lad;
        }
        __syncthreads();   // spline reads done before next pass overwrites sP
    }
}

extern "C" void kernel_launch(void* const* d_in, const int* in_sizes, int n_in,
                              void* d_out, int out_size, void* d_ws, size_t ws_size,
                              hipStream_t stream) {
    const float* theta = (const float*)d_in[0];
    const float* X     = (const float*)d_in[1];
    const float* W1    = (const float*)d_in[2];
    const float* b1    = (const float*)d_in[3];
    const float* W2    = (const float*)d_in[4];
    const float* b2    = (const float*)d_in[5];
    const float* eta   = (const float*)d_in[6];
    float* out = (float*)d_out;

    short* W2p_hi = (short*)d_ws;                        // 384 KB
    short* W2p_lo = W2p_hi + W2P_ELEMS;                  // 384 KB
    short* W1p_hi = W2p_lo + W2P_ELEMS;                  //  32 KB
    short* W1p_lo = W1p_hi + W1P_ELEMS;                  //  32 KB

    pack_weights<<<(W2P_ELEMS + W1P_ELEMS) / 256, 256, 0, stream>>>(
        W1, W2, W1p_hi, W1p_lo, W2p_hi, W2p_lo);

    (void)hipFuncSetAttribute((const void*)spline_mfma,
                              hipFuncAttributeMaxDynamicSharedMemorySize,
                              LDS_BYTES);
    const int blocks = B_TOTAL / R_ROWS;  // 2048
    spline_mfma<<<blocks, NTHREADS, LDS_BYTES, stream>>>(
        theta, X, W1p_hi, W1p_lo, b1, W2p_hi, W2p_lo, b2, eta, out);
}